// Round 8
// baseline (87.023 us; speedup 1.0000x reference)
//
#include <hip/hip_runtime.h>
#include <cstdint>

#define IN_DIM   128
#define OUT_DIM  256
#define NROWS    32768
#define BM       64            // rows per block
#define NSTEPS_L 16            // per-group K-tiles: K_half = 2048 = 16 * 128
#define STR      65            // bf16x8 row stride (64 + 1 pad)

typedef unsigned short u16;
typedef __attribute__((ext_vector_type(8)))  __bf16 bf16x8;
typedef __attribute__((ext_vector_type(16))) float  f32x16;

// ---------------------------------------------------------------------------
// Prep: repack fouriercoeffs (2,256,128,16) f32 -> Bpack bf16 [K/8][256][8]
// with k = i*32 + t*16 + g  (t: 0=cos, 1=sin; slot g holds harmonic g+1).
// ---------------------------------------------------------------------------
__global__ __launch_bounds__(256) void kan_prep(const float* __restrict__ C,
                                                u16* __restrict__ Bpack) {
    const int o = threadIdx.x;   // 0..255 output channel
    const int i = blockIdx.x;    // 0..127 input dim
    const int t = blockIdx.y;    // 0=cos, 1=sin
    const float* src = C + (((size_t)(t * OUT_DIM + o) * IN_DIM + i) * 16);
    bf16x8 lo = {}, hi = {};
#pragma unroll
    for (int g = 0; g < 8; ++g) {
        lo[g] = (__bf16)src[g];
        hi[g] = (__bf16)src[8 + g];
    }
    const int ko = i * 4 + t * 2;       // k>>3
    bf16x8* dst = (bf16x8*)Bpack;
    dst[(size_t)ko * OUT_DIM + o]       = lo;   // g = 0..7
    dst[(size_t)(ko + 1) * OUT_DIM + o] = hi;   // g = 8..15
}

// ---------------------------------------------------------------------------
// Fused trig + bf16 MFMA GEMM, v8 = v7 + in-block K-split for occupancy.
//  - 512 threads = 2 groups x 4 waves. Group kh owns i in [64*kh, 64*kh+64)
//    (K-half), runs v7's exact loop on its own double-buffered A-LDS with
//    its own trig tasks (disjoint i-ranges: still zero trig redundancy).
//    NO conditionals in the main loop (v4's failure class eliminated).
//  - 2 blocks/CU (LDS 65KB, VGPR<=128 via launch_bounds(512,4)) -> 16
//    waves/CU = 4 waves/SIMD: TLP hides the per-kw B-L2 latency that v7's
//    register-starved prefetch could not (VGPR_Count=92 proved the compiler
//    rematerialized the full-kt prefetch).
//  - B: plain per-kw register loads (8 VGPR transient), 1/64 B/FLOP kept.
//  - Merge: group1 dumps acc (f32) into the A-LDS space after the last
//    barrier; group0 adds, + bias, stores. Same [row][col] expression on
//    both sides; fp-add commutativity irrelevant (fixed order) -> exact.
// ---------------------------------------------------------------------------
__global__ __launch_bounds__(512, 4) void kan_gemm(const float* __restrict__ x,
                                                   const u16* __restrict__ Bpack,
                                                   const float* __restrict__ bias,
                                                   float* __restrict__ out) {
    __shared__ __align__(16) u16 Asm[2][2][16 * STR * 8];   // [group][buf] 65 KB

    const int tid  = threadIdx.x;
    const int lane = tid & 63;
    const int wid  = tid >> 6;       // 0..7
    const int kh   = wid >> 2;       // 0..1  K-half group
    const int wn   = wid & 3;        // 0..3  col block (64 cols) within group
    const int la31 = lane & 31;
    const int gh   = lane >> 5;      // 0..1  k-half within a K=16 window
    const int m0   = blockIdx.x * BM;

    // trig task mapping within group: 256 tasks = 64 rows x 4 i-subs
    const int tl  = tid & 255;       // id within group
    const int tr  = tl >> 2;         // 0..63 row
    const int til = tl & 3;          // 0..3, i = kh*64 + ktL*4 + til

    f32x16 vz;
#pragma unroll
    for (int r = 0; r < 16; ++r) vz[r] = 0.f;
    f32x16 acc[2][2] = {{vz, vz}, {vz, vz}};

    const bf16x8* Bv = (const bf16x8*)Bpack;
    // group's B base: ko offset = kh * (2048/8) = kh*256 rows of OUT_DIM
    const bf16x8* Bg = Bv + (size_t)kh * 256 * OUT_DIM;
    bf16x8* Av0 = (bf16x8*)Asm[kh][0];
    bf16x8* Av1 = (bf16x8*)Asm[kh][1];

    const float* xrow = x + (size_t)(m0 + tr) * IN_DIM + kh * 64 + til;
    const int bcol = wn * 64 + la31;           // + fn*32 per fragment

    // ---- harmonic generator (v7 verbatim): 4 ds_write_b128 ----
    auto gen = [&](bf16x8* Av, float xv) {
        float s1, c1;
        __sincosf(xv, &s1, &c1);
        const float t2 = 2.f * c1;
        bf16x8 qc0 = {}, qc1 = {}, qs0 = {}, qs1 = {};
        float cp = c1, sp = s1;                    // harmonic 1
        float cc = t2 * c1 - 1.f, sc = t2 * s1;    // harmonic 2
        qc0[0] = (__bf16)cp;  qs0[0] = (__bf16)sp;
        qc0[1] = (__bf16)cc;  qs0[1] = (__bf16)sc;
#pragma unroll
        for (int g = 3; g <= 16; ++g) {            // Chebyshev: 2 FMA each
            const float cn = t2 * cc - cp;
            const float sn = t2 * sc - sp;
            cp = cc; sp = sc; cc = cn; sc = sn;
            const int idx = g - 1;                 // slot = harmonic-1
            if (idx < 8) { qc0[idx] = (__bf16)cc;      qs0[idx] = (__bf16)sc; }
            else         { qc1[idx - 8] = (__bf16)cc;  qs1[idx - 8] = (__bf16)sc; }
        }
        const int kob = til * 4;   // local ko = til*4 + t*2 + (g>>3)
        Av[(kob + 0) * STR + tr] = qc0;
        Av[(kob + 1) * STR + tr] = qc1;
        Av[(kob + 2) * STR + tr] = qs0;
        Av[(kob + 3) * STR + tr] = qs1;
    };

    // prologue: gen tile 0 of this group's K-half
    float xn = xrow[4];
    gen(Av0, xrow[0]);
    __syncthreads();

    for (int ktL = 0; ktL < NSTEPS_L; ++ktL) {
        bf16x8* Avc = (ktL & 1) ? Av1 : Av0;
        bf16x8* Avn = (ktL & 1) ? Av0 : Av1;

        // generate next A tile (VALU) — interleaves with this tile's MFMAs
        if (ktL + 1 < NSTEPS_L) {
            gen(Avn, xn);
            xn = xrow[((ktL + 2) & (NSTEPS_L - 1)) * 4];
        }

#pragma unroll
        for (int kw = 0; kw < 8; ++kw) {
            const int koL = (kw >> 1) * 4 + (kw & 1) * 2 + gh;
            bf16x8 bg[2];
#pragma unroll
            for (int fn = 0; fn < 2; ++fn)
                bg[fn] = Bg[(size_t)(ktL * 16 + koL) * OUT_DIM + bcol + fn * 32];
            bf16x8 af[2];
#pragma unroll
            for (int fm = 0; fm < 2; ++fm)
                af[fm] = Avc[koL * STR + fm * 32 + la31];
#pragma unroll
            for (int fm = 0; fm < 2; ++fm)
#pragma unroll
                for (int fn = 0; fn < 2; ++fn)
                    acc[fm][fn] = __builtin_amdgcn_mfma_f32_32x32x16_bf16(
                        af[fm], bg[fn], acc[fm][fn], 0, 0, 0);
        }
        __syncthreads();
    }

    // ---- merge the two K-half partials through LDS ----
    // After the loop's final barrier all A-LDS reads are done; reuse as f32
    // scratch [64][256] (65536 B <= 66560 B).
    float* redf = (float*)&Asm[0][0][0];
    if (kh == 1) {
#pragma unroll
        for (int fm = 0; fm < 2; ++fm)
#pragma unroll
            for (int fn = 0; fn < 2; ++fn) {
                const int col = wn * 64 + fn * 32 + la31;
#pragma unroll
                for (int r = 0; r < 16; ++r) {
                    const int row = fm * 32 + 4 * gh + (r & 3) + 8 * (r >> 2);
                    redf[row * OUT_DIM + col] = acc[fm][fn][r];
                }
            }
    }
    __syncthreads();
    if (kh == 0) {
#pragma unroll
        for (int fn = 0; fn < 2; ++fn) {
            const int col = wn * 64 + fn * 32 + la31;
            const float bv = bias[col];
#pragma unroll
            for (int fm = 0; fm < 2; ++fm) {
#pragma unroll
                for (int r = 0; r < 16; ++r) {
                    const int row = fm * 32 + 4 * gh + (r & 3) + 8 * (r >> 2);
                    out[(size_t)(m0 + row) * OUT_DIM + col] =
                        acc[fm][fn][r] + redf[row * OUT_DIM + col] + bv;
                }
            }
        }
    }
}

extern "C" void kernel_launch(void* const* d_in, const int* in_sizes, int n_in,
                              void* d_out, int out_size, void* d_ws, size_t ws_size,
                              hipStream_t stream) {
    const float* x    = (const float*)d_in[0];   // (32768, 128) f32
    const float* fc   = (const float*)d_in[1];   // (2, 256, 128, 16) f32
    const float* bias = (const float*)d_in[2];   // (1, 256) f32
    float* out        = (float*)d_out;           // (32768, 256) f32
    u16* Bpack        = (u16*)d_ws;              // 4096*256*2 B = 2 MB scratch

    kan_prep<<<dim3(IN_DIM, 2), OUT_DIM, 0, stream>>>(fc, Bpack);
    kan_gemm<<<dim3(NROWS / BM), 512, 0, stream>>>(x, Bpack, bias, out);
}

// Round 9
// 82.129 us; speedup vs baseline: 1.0596x; 1.0596x over previous
//
#include <hip/hip_runtime.h>
#include <cstdint>

#define IN_DIM   128
#define OUT_DIM  256
#define NROWS    32768
#define BM       64            // rows per block
#define NSTEPS   32            // K = 4096 = 32 * 128 (BK=128: 4 i-values/step)
#define STR      65            // bf16x8 row stride (64 + 1 pad)

typedef unsigned short u16;
typedef __attribute__((ext_vector_type(8)))  __bf16 bf16x8;
typedef __attribute__((ext_vector_type(16))) float  f32x16;

// ---------------------------------------------------------------------------
// Prep: repack fouriercoeffs (2,256,128,16) f32 -> Bpack bf16 [K/8][256][8]
// with k = i*32 + t*16 + g  (t: 0=cos, 1=sin; slot g holds harmonic g+1).
// ---------------------------------------------------------------------------
__global__ __launch_bounds__(256) void kan_prep(const float* __restrict__ C,
                                                u16* __restrict__ Bpack) {
    const int o = threadIdx.x;   // 0..255 output channel
    const int i = blockIdx.x;    // 0..127 input dim
    const int t = blockIdx.y;    // 0=cos, 1=sin
    const float* src = C + (((size_t)(t * OUT_DIM + o) * IN_DIM + i) * 16);
    bf16x8 lo = {}, hi = {};
#pragma unroll
    for (int g = 0; g < 8; ++g) {
        lo[g] = (__bf16)src[g];
        hi[g] = (__bf16)src[8 + g];
    }
    const int ko = i * 4 + t * 2;       // k>>3
    bf16x8* dst = (bf16x8*)Bpack;
    dst[(size_t)ko * OUT_DIM + o]       = lo;   // g = 0..7
    dst[(size_t)(ko + 1) * OUT_DIM + o] = hi;   // g = 8..15
}

// ---------------------------------------------------------------------------
// Fused trig + bf16 MFMA GEMM, v9 = v7 + un-defeatable B software pipeline.
//  - v7's wall (measured): per-kw B L2 loads (~200-400cy) fully exposed;
//    VGPR_Count=92 proved the compiler folded the array-copy prefetch.
//  - Fix: two statically-indexed fragment sets bA/bB, NO copies. Per kt:
//      issue bB (kw4-7 of kt) -> gen(kt+1) -> MFMA kw0-3 from bA (loaded
//      last kt, >=1000cy distance) -> issue bA (kw0-3 of kt+1) -> MFMA
//      kw4-7 from bB (>=800cy distance) -> barrier.
//    Load-to-use distance >= 2x L2 latency at every use site.
//  - launch_bounds(256,2): VGPR cap 256; need ~170 (acc 64 + B 64 + misc).
//  - Everything else v7-verbatim: BM=64, BK=128, 4 waves 64x64 (fm2 x fn2
//    of 32x32x16), dbuf A-LDS STR=65, gen, epilogue, 1/64+1/64 ledger.
// ---------------------------------------------------------------------------
__global__ __launch_bounds__(256, 2) void kan_gemm(const float* __restrict__ x,
                                                   const u16* __restrict__ Bpack,
                                                   const float* __restrict__ bias,
                                                   float* __restrict__ out) {
    __shared__ __align__(16) u16 Asm[2][16 * STR * 8];   // 2 x 16640 B

    const int tid  = threadIdx.x;
    const int lane = tid & 63;
    const int wn   = tid >> 6;       // 0..3  col block (64 cols)
    const int la31 = lane & 31;
    const int gh   = lane >> 5;      // 0..1  k-half within a K=16 window
    const int m0   = blockIdx.x * BM;

    // trig task mapping: thread -> (row tr, i-sub til), i = kt*4 + til
    const int tr  = tid >> 2;        // 0..63
    const int til = tid & 3;         // 0..3

    f32x16 vz;
#pragma unroll
    for (int r = 0; r < 16; ++r) vz[r] = 0.f;
    f32x16 acc[2][2] = {{vz, vz}, {vz, vz}};

    const bf16x8* Bv = (const bf16x8*)Bpack;
    bf16x8* Av0 = (bf16x8*)Asm[0];
    bf16x8* Av1 = (bf16x8*)Asm[1];

    const float* xrow = x + (size_t)(m0 + tr) * IN_DIM + til;
    const int bcol = wn * 64 + la31;           // + fn*32 per fragment

    // ---- harmonic generator (v7 verbatim): 4 ds_write_b128 ----
    auto gen = [&](bf16x8* Av, float xv) {
        float s1, c1;
        __sincosf(xv, &s1, &c1);
        const float t2 = 2.f * c1;
        bf16x8 qc0 = {}, qc1 = {}, qs0 = {}, qs1 = {};
        float cp = c1, sp = s1;                    // harmonic 1
        float cc = t2 * c1 - 1.f, sc = t2 * s1;    // harmonic 2
        qc0[0] = (__bf16)cp;  qs0[0] = (__bf16)sp;
        qc0[1] = (__bf16)cc;  qs0[1] = (__bf16)sc;
#pragma unroll
        for (int g = 3; g <= 16; ++g) {            // Chebyshev: 2 FMA each
            const float cn = t2 * cc - cp;
            const float sn = t2 * sc - sp;
            cp = cc; sp = sc; cc = cn; sc = sn;
            const int idx = g - 1;                 // slot = harmonic-1
            if (idx < 8) { qc0[idx] = (__bf16)cc;      qs0[idx] = (__bf16)sc; }
            else         { qc1[idx - 8] = (__bf16)cc;  qs1[idx - 8] = (__bf16)sc; }
        }
        const int kob = til * 4;   // local ko = til*4 + t*2 + (g>>3)
        Av[(kob + 0) * STR + tr] = qc0;
        Av[(kob + 1) * STR + tr] = qc1;
        Av[(kob + 2) * STR + tr] = qs0;
        Av[(kob + 3) * STR + tr] = qs1;
    };

    // B fragment pipeline: bA holds kw0-3, bB holds kw4-7 (static idx only).
    // local ko(kw, gh) = (kw>>1)*4 + (kw&1)*2 + gh
    bf16x8 bA[8], bB[8];

    // prologue: bA <- kt0 kw0-3; gen tile 0; x for tile 1
#pragma unroll
    for (int j = 0; j < 4; ++j)
#pragma unroll
        for (int fn = 0; fn < 2; ++fn)
            bA[j * 2 + fn] = Bv[(size_t)((j >> 1) * 4 + (j & 1) * 2 + gh) * OUT_DIM
                                + bcol + fn * 32];
    float xn = xrow[4];
    gen(Av0, xrow[0]);
    __syncthreads();

    for (int kt = 0; kt < NSTEPS; ++kt) {
        bf16x8* Avc = (kt & 1) ? Av1 : Av0;
        bf16x8* Avn = (kt & 1) ? Av0 : Av1;

        // issue bB: kw4-7 of THIS kt (used ~800cy later, after gen + 16 MFMA)
#pragma unroll
        for (int j = 0; j < 4; ++j)
#pragma unroll
            for (int fn = 0; fn < 2; ++fn)
                bB[j * 2 + fn] = Bv[(size_t)(kt * 16 + 8 + (j >> 1) * 4 + (j & 1) * 2 + gh)
                                    * OUT_DIM + bcol + fn * 32];

        // generate next A tile (VALU) — fills the bB load shadow
        if (kt + 1 < NSTEPS) {
            gen(Avn, xn);
            xn = xrow[((kt + 2) & (NSTEPS - 1)) * 4];
        }

        // MFMA kw0-3 from bA (loaded last kt: >=1000cy in flight)
#pragma unroll
        for (int j = 0; j < 4; ++j) {
            const int koL = (j >> 1) * 4 + (j & 1) * 2 + gh;
            const bf16x8 af0 = Avc[koL * STR + la31];
            const bf16x8 af1 = Avc[koL * STR + 32 + la31];
            acc[0][0] = __builtin_amdgcn_mfma_f32_32x32x16_bf16(af0, bA[j*2+0], acc[0][0], 0, 0, 0);
            acc[0][1] = __builtin_amdgcn_mfma_f32_32x32x16_bf16(af0, bA[j*2+1], acc[0][1], 0, 0, 0);
            acc[1][0] = __builtin_amdgcn_mfma_f32_32x32x16_bf16(af1, bA[j*2+0], acc[1][0], 0, 0, 0);
            acc[1][1] = __builtin_amdgcn_mfma_f32_32x32x16_bf16(af1, bA[j*2+1], acc[1][1], 0, 0, 0);
        }

        // issue bA: kw0-3 of NEXT kt (used next iteration, cross-barrier)
        {
            const int ktn = (kt + 1) & (NSTEPS - 1);
#pragma unroll
            for (int j = 0; j < 4; ++j)
#pragma unroll
                for (int fn = 0; fn < 2; ++fn)
                    bA[j * 2 + fn] = Bv[(size_t)(ktn * 16 + (j >> 1) * 4 + (j & 1) * 2 + gh)
                                        * OUT_DIM + bcol + fn * 32];
        }

        // MFMA kw4-7 from bB
#pragma unroll
        for (int j = 0; j < 4; ++j) {
            const int koL = 8 + (j >> 1) * 4 + (j & 1) * 2 + gh;
            const bf16x8 af0 = Avc[koL * STR + la31];
            const bf16x8 af1 = Avc[koL * STR + 32 + la31];
            acc[0][0] = __builtin_amdgcn_mfma_f32_32x32x16_bf16(af0, bB[j*2+0], acc[0][0], 0, 0, 0);
            acc[0][1] = __builtin_amdgcn_mfma_f32_32x32x16_bf16(af0, bB[j*2+1], acc[0][1], 0, 0, 0);
            acc[1][0] = __builtin_amdgcn_mfma_f32_32x32x16_bf16(af1, bB[j*2+0], acc[1][0], 0, 0, 0);
            acc[1][1] = __builtin_amdgcn_mfma_f32_32x32x16_bf16(af1, bB[j*2+1], acc[1][1], 0, 0, 0);
        }
        __syncthreads();
    }

    // ---- epilogue (v7 verbatim): col=lane&31, row=(r&3)+8*(r>>2)+4*gh ----
#pragma unroll
    for (int fn = 0; fn < 2; ++fn) {
        const int col = bcol + fn * 32;
        const float bv = bias[col];
#pragma unroll
        for (int fm = 0; fm < 2; ++fm) {
            const int rbase = m0 + fm * 32 + 4 * gh;
#pragma unroll
            for (int r = 0; r < 16; ++r) {
                const int row = rbase + (r & 3) + 8 * (r >> 2);
                out[(size_t)row * OUT_DIM + col] = acc[fm][fn][r] + bv;
            }
        }
    }
}

extern "C" void kernel_launch(void* const* d_in, const int* in_sizes, int n_in,
                              void* d_out, int out_size, void* d_ws, size_t ws_size,
                              hipStream_t stream) {
    const float* x    = (const float*)d_in[0];   // (32768, 128) f32
    const float* fc   = (const float*)d_in[1];   // (2, 256, 128, 16) f32
    const float* bias = (const float*)d_in[2];   // (1, 256) f32
    float* out        = (float*)d_out;           // (32768, 256) f32
    u16* Bpack        = (u16*)d_ws;              // 4096*256*2 B = 2 MB scratch

    kan_prep<<<dim3(IN_DIM, 2), OUT_DIM, 0, stream>>>(fc, Bpack);
    kan_gemm<<<dim3(NROWS / BM), 256, 0, stream>>>(x, Bpack, bias, out);
}

// Round 10
// 81.294 us; speedup vs baseline: 1.0705x; 1.0103x over previous
//
#include <hip/hip_runtime.h>
#include <cstdint>

#define IN_DIM   128
#define OUT_DIM  256
#define NROWS    32768
#define BM       64            // rows per block
#define NSTEPS   32            // K = 4096 = 32 * 128 (BK=128: 4 i-values/step)
#define STR      65            // bf16x8 row stride (64 + 1 pad)

typedef unsigned short u16;
typedef __attribute__((ext_vector_type(8)))  __bf16 bf16x8;
typedef __attribute__((ext_vector_type(16))) float  f32x16;

// lgkm-only barrier: drains LDS ops (cross-wave visibility) but leaves
// global B loads in flight across the barrier (T4: never vmcnt(0) in-loop).
// __syncthreads() would emit s_waitcnt vmcnt(0) lgkmcnt(0) — the measured
// ~63%-stall structural drain.
#define BARRIER_LGKM()                                         \
    do {                                                       \
        asm volatile("s_waitcnt lgkmcnt(0)" ::: "memory");     \
        __builtin_amdgcn_s_barrier();                          \
    } while (0)

// ---------------------------------------------------------------------------
// Prep: repack fouriercoeffs (2,256,128,16) f32 -> Bpack bf16 [K/8][256][8]
// with k = i*32 + t*16 + g  (t: 0=cos, 1=sin; slot g holds harmonic g+1).
// ---------------------------------------------------------------------------
__global__ __launch_bounds__(256) void kan_prep(const float* __restrict__ C,
                                                u16* __restrict__ Bpack) {
    const int o = threadIdx.x;   // 0..255 output channel
    const int i = blockIdx.x;    // 0..127 input dim
    const int t = blockIdx.y;    // 0=cos, 1=sin
    const float* src = C + (((size_t)(t * OUT_DIM + o) * IN_DIM + i) * 16);
    bf16x8 lo = {}, hi = {};
#pragma unroll
    for (int g = 0; g < 8; ++g) {
        lo[g] = (__bf16)src[g];
        hi[g] = (__bf16)src[8 + g];
    }
    const int ko = i * 4 + t * 2;       // k>>3
    bf16x8* dst = (bf16x8*)Bpack;
    dst[(size_t)ko * OUT_DIM + o]       = lo;   // g = 0..7
    dst[(size_t)(ko + 1) * OUT_DIM + o] = hi;   // g = 8..15
}

// ---------------------------------------------------------------------------
// Fused trig + bf16 MFMA GEMM, v10 = v9 + lgkm-only barrier (ONE change).
//  - v5/v7/v9 invariant: wall ~5500 cy/kt vs 2048 cy max pipe. The per-kt
//    __syncthreads drained vmcnt(0): one exposed L2 latency per kt AND no
//    cross-kt B prefetch possible. Raw s_barrier + lgkmcnt(0) keeps B loads
//    in flight across the barrier; compiler's own counted-vmcnt places the
//    wait at first use (~600+cy after issue) -> hidden under gen + MFMA.
//  - Correctness: kt-barrier only guards LDS (dbuf gen-write/read hazards);
//    lgkmcnt(0)-before-barrier per wave is sufficient. B loads never touch
//    LDS. "memory" clobber pins ds ops on the correct side of the asm.
//  - Everything else v9-verbatim: BM=64, BK=128, 4 waves 64x64 (fm2 x fn2 of
//    32x32x16), dbuf A-LDS STR=65, bA/bB two-cluster B pipeline, gen,
//    epilogue, 1/64+1/64 traffic ledger.
// ---------------------------------------------------------------------------
__global__ __launch_bounds__(256, 2) void kan_gemm(const float* __restrict__ x,
                                                   const u16* __restrict__ Bpack,
                                                   const float* __restrict__ bias,
                                                   float* __restrict__ out) {
    __shared__ __align__(16) u16 Asm[2][16 * STR * 8];   // 2 x 16640 B

    const int tid  = threadIdx.x;
    const int lane = tid & 63;
    const int wn   = tid >> 6;       // 0..3  col block (64 cols)
    const int la31 = lane & 31;
    const int gh   = lane >> 5;      // 0..1  k-half within a K=16 window
    const int m0   = blockIdx.x * BM;

    // trig task mapping: thread -> (row tr, i-sub til), i = kt*4 + til
    const int tr  = tid >> 2;        // 0..63
    const int til = tid & 3;         // 0..3

    f32x16 vz;
#pragma unroll
    for (int r = 0; r < 16; ++r) vz[r] = 0.f;
    f32x16 acc[2][2] = {{vz, vz}, {vz, vz}};

    const bf16x8* Bv = (const bf16x8*)Bpack;
    bf16x8* Av0 = (bf16x8*)Asm[0];
    bf16x8* Av1 = (bf16x8*)Asm[1];

    const float* xrow = x + (size_t)(m0 + tr) * IN_DIM + til;
    const int bcol = wn * 64 + la31;           // + fn*32 per fragment

    // ---- harmonic generator (v7 verbatim): 4 ds_write_b128 ----
    auto gen = [&](bf16x8* Av, float xv) {
        float s1, c1;
        __sincosf(xv, &s1, &c1);
        const float t2 = 2.f * c1;
        bf16x8 qc0 = {}, qc1 = {}, qs0 = {}, qs1 = {};
        float cp = c1, sp = s1;                    // harmonic 1
        float cc = t2 * c1 - 1.f, sc = t2 * s1;    // harmonic 2
        qc0[0] = (__bf16)cp;  qs0[0] = (__bf16)sp;
        qc0[1] = (__bf16)cc;  qs0[1] = (__bf16)sc;
#pragma unroll
        for (int g = 3; g <= 16; ++g) {            // Chebyshev: 2 FMA each
            const float cn = t2 * cc - cp;
            const float sn = t2 * sc - sp;
            cp = cc; sp = sc; cc = cn; sc = sn;
            const int idx = g - 1;                 // slot = harmonic-1
            if (idx < 8) { qc0[idx] = (__bf16)cc;      qs0[idx] = (__bf16)sc; }
            else         { qc1[idx - 8] = (__bf16)cc;  qs1[idx - 8] = (__bf16)sc; }
        }
        const int kob = til * 4;   // local ko = til*4 + t*2 + (g>>3)
        Av[(kob + 0) * STR + tr] = qc0;
        Av[(kob + 1) * STR + tr] = qc1;
        Av[(kob + 2) * STR + tr] = qs0;
        Av[(kob + 3) * STR + tr] = qs1;
    };

    // B fragment pipeline: bA holds kw0-3, bB holds kw4-7 (static idx only).
    // local ko(kw, gh) = (kw>>1)*4 + (kw&1)*2 + gh
    bf16x8 bA[8], bB[8];

    // prologue: bA <- kt0 kw0-3; gen tile 0; x for tile 1
#pragma unroll
    for (int j = 0; j < 4; ++j)
#pragma unroll
        for (int fn = 0; fn < 2; ++fn)
            bA[j * 2 + fn] = Bv[(size_t)((j >> 1) * 4 + (j & 1) * 2 + gh) * OUT_DIM
                                + bcol + fn * 32];
    float xn = xrow[4];
    gen(Av0, xrow[0]);
    BARRIER_LGKM();

    for (int kt = 0; kt < NSTEPS; ++kt) {
        bf16x8* Avc = (kt & 1) ? Av1 : Av0;
        bf16x8* Avn = (kt & 1) ? Av0 : Av1;

        // issue bB: kw4-7 of THIS kt (used after gen + 16 MFMA)
#pragma unroll
        for (int j = 0; j < 4; ++j)
#pragma unroll
            for (int fn = 0; fn < 2; ++fn)
                bB[j * 2 + fn] = Bv[(size_t)(kt * 16 + 8 + (j >> 1) * 4 + (j & 1) * 2 + gh)
                                    * OUT_DIM + bcol + fn * 32];

        // generate next A tile (VALU) — fills the bB load shadow
        if (kt + 1 < NSTEPS) {
            gen(Avn, xn);
            xn = xrow[((kt + 2) & (NSTEPS - 1)) * 4];
        }

        // MFMA kw0-3 from bA (in flight across the previous barrier)
#pragma unroll
        for (int j = 0; j < 4; ++j) {
            const int koL = (j >> 1) * 4 + (j & 1) * 2 + gh;
            const bf16x8 af0 = Avc[koL * STR + la31];
            const bf16x8 af1 = Avc[koL * STR + 32 + la31];
            acc[0][0] = __builtin_amdgcn_mfma_f32_32x32x16_bf16(af0, bA[j*2+0], acc[0][0], 0, 0, 0);
            acc[0][1] = __builtin_amdgcn_mfma_f32_32x32x16_bf16(af0, bA[j*2+1], acc[0][1], 0, 0, 0);
            acc[1][0] = __builtin_amdgcn_mfma_f32_32x32x16_bf16(af1, bA[j*2+0], acc[1][0], 0, 0, 0);
            acc[1][1] = __builtin_amdgcn_mfma_f32_32x32x16_bf16(af1, bA[j*2+1], acc[1][1], 0, 0, 0);
        }

        // issue bA: kw0-3 of NEXT kt (stays in flight across the barrier)
        {
            const int ktn = (kt + 1) & (NSTEPS - 1);
#pragma unroll
            for (int j = 0; j < 4; ++j)
#pragma unroll
                for (int fn = 0; fn < 2; ++fn)
                    bA[j * 2 + fn] = Bv[(size_t)(ktn * 16 + (j >> 1) * 4 + (j & 1) * 2 + gh)
                                        * OUT_DIM + bcol + fn * 32];
        }

        // MFMA kw4-7 from bB
#pragma unroll
        for (int j = 0; j < 4; ++j) {
            const int koL = 8 + (j >> 1) * 4 + (j & 1) * 2 + gh;
            const bf16x8 af0 = Avc[koL * STR + la31];
            const bf16x8 af1 = Avc[koL * STR + 32 + la31];
            acc[0][0] = __builtin_amdgcn_mfma_f32_32x32x16_bf16(af0, bB[j*2+0], acc[0][0], 0, 0, 0);
            acc[0][1] = __builtin_amdgcn_mfma_f32_32x32x16_bf16(af0, bB[j*2+1], acc[0][1], 0, 0, 0);
            acc[1][0] = __builtin_amdgcn_mfma_f32_32x32x16_bf16(af1, bB[j*2+0], acc[1][0], 0, 0, 0);
            acc[1][1] = __builtin_amdgcn_mfma_f32_32x32x16_bf16(af1, bB[j*2+1], acc[1][1], 0, 0, 0);
        }
        BARRIER_LGKM();
    }

    // ---- epilogue (v7 verbatim): col=lane&31, row=(r&3)+8*(r>>2)+4*gh ----
#pragma unroll
    for (int fn = 0; fn < 2; ++fn) {
        const int col = bcol + fn * 32;
        const float bv = bias[col];
#pragma unroll
        for (int fm = 0; fm < 2; ++fm) {
            const int rbase = m0 + fm * 32 + 4 * gh;
#pragma unroll
            for (int r = 0; r < 16; ++r) {
                const int row = rbase + (r & 3) + 8 * (r >> 2);
                out[(size_t)row * OUT_DIM + col] = acc[fm][fn][r] + bv;
            }
        }
    }
}

extern "C" void kernel_launch(void* const* d_in, const int* in_sizes, int n_in,
                              void* d_out, int out_size, void* d_ws, size_t ws_size,
                              hipStream_t stream) {
    const float* x    = (const float*)d_in[0];   // (32768, 128) f32
    const float* fc   = (const float*)d_in[1];   // (2, 256, 128, 16) f32
    const float* bias = (const float*)d_in[2];   // (1, 256) f32
    float* out        = (float*)d_out;           // (32768, 256) f32
    u16* Bpack        = (u16*)d_ws;              // 4096*256*2 B = 2 MB scratch

    kan_prep<<<dim3(IN_DIM, 2), OUT_DIM, 0, stream>>>(fc, Bpack);
    kan_gemm<<<dim3(NROWS / BM), 256, 0, stream>>>(x, Bpack, bias, out);
}